// Round 12
// baseline (6373.944 us; speedup 1.0000x reference)
//
#include <hip/hip_runtime.h>
#include <math.h>

#define TSTEPS 100
#define BB 256
#define FF 1024
#define NIN 784
#define NW 13           // 13*64 = 832 >= 784 bits per input row
#define CAPA 192        // max pre-spikes per (t,b)
#define CAPB 128        // max pre-spikes per (t,i)
#define NBLK 512        // 2 blocks/CU
#define TPB 512         // 8 waves/block
#define BARSZ 8704      // u32: slots[512] + arrive[8*512] + release[8*512]

typedef unsigned long long u64;
typedef float f4 __attribute__((ext_vector_type(4)));

// agent-scope atomics — ONLY for self-org + barrier flags (off hot path)
__device__ __forceinline__ unsigned at_ld(unsigned* p) {
    return __hip_atomic_load(p, __ATOMIC_RELAXED, __HIP_MEMORY_SCOPE_AGENT);
}
__device__ __forceinline__ void at_st(unsigned* p, unsigned v) {
    __hip_atomic_store(p, v, __ATOMIC_RELAXED, __HIP_MEMORY_SCOPE_AGENT);
}

// L1-bypassing loads (r10/r11-proven); values served from XCD-local L2
__device__ __forceinline__ float sc0_ld(const float* p) {
    float v;
    asm volatile("global_load_dword %0, %1, off sc0\n\t"
                 "s_waitcnt vmcnt(0)"
                 : "=v"(v) : "v"(p) : "memory");
    __builtin_amdgcn_sched_barrier(0);
    return v;
}
__device__ __forceinline__ f4 sc0_ld4(const f4* p) {
    f4 v;
    asm volatile("global_load_dwordx4 %0, %1, off sc0\n\t"
                 "s_waitcnt vmcnt(0)"
                 : "=v"(v) : "v"(p) : "memory");
    __builtin_amdgcn_sched_barrier(0);
    return v;
}
__device__ __forceinline__ void sc0_ld64x4(
    const u64* p0, const u64* p1, const u64* p2, const u64* p3,
    u64& a, u64& b, u64& c, u64& d)
{
    asm volatile(
        "global_load_dwordx2 %0, %4, off sc0\n\t"
        "global_load_dwordx2 %1, %5, off sc0\n\t"
        "global_load_dwordx2 %2, %6, off sc0\n\t"
        "global_load_dwordx2 %3, %7, off sc0\n\t"
        "s_waitcnt vmcnt(0)"
        : "=&v"(a),"=&v"(b),"=&v"(c),"=&v"(d)
        : "v"(p0),"v"(p1),"v"(p2),"v"(p3) : "memory");
    __builtin_amdgcn_sched_barrier(0);
}
__device__ __forceinline__ void sc0_issue8(
    const float* p0, const float* p1, const float* p2, const float* p3,
    const float* p4, const float* p5, const float* p6, const float* p7,
    float& v0, float& v1, float& v2, float& v3,
    float& v4, float& v5, float& v6, float& v7)
{
    asm volatile(
        "global_load_dword %0, %8, off sc0\n\t"
        "global_load_dword %1, %9, off sc0\n\t"
        "global_load_dword %2, %10, off sc0\n\t"
        "global_load_dword %3, %11, off sc0\n\t"
        "global_load_dword %4, %12, off sc0\n\t"
        "global_load_dword %5, %13, off sc0\n\t"
        "global_load_dword %6, %14, off sc0\n\t"
        "global_load_dword %7, %15, off sc0"
        : "=&v"(v0),"=&v"(v1),"=&v"(v2),"=&v"(v3),
          "=&v"(v4),"=&v"(v5),"=&v"(v6),"=&v"(v7)
        : "v"(p0),"v"(p1),"v"(p2),"v"(p3),"v"(p4),"v"(p5),"v"(p6),"v"(p7)
        : "memory");
}
__device__ __forceinline__ void sc0_ld8(
    const float* p0, const float* p1, const float* p2, const float* p3,
    const float* p4, const float* p5, const float* p6, const float* p7,
    float& v0, float& v1, float& v2, float& v3,
    float& v4, float& v5, float& v6, float& v7)
{
    sc0_issue8(p0,p1,p2,p3,p4,p5,p6,p7, v0,v1,v2,v3,v4,v5,v6,v7);
    asm volatile("s_waitcnt vmcnt(0)" ::: "memory");
    __builtin_amdgcn_sched_barrier(0);
}

// sequential f32 fold over base[list[k]<<10 + f], ascending k — the VERIFIED
// numpy fold order; batching changes only load timing, never add order.
template <typename IDX>
__device__ __forceinline__ float foldList(
    const float* __restrict__ base, const IDX* __restrict__ list,
    int k0, int k1, int f)
{
    float c = 0.f;
    int k = k0;
    for (; k + 16 <= k1; k += 16) {
        float v0,v1,v2,v3,v4,v5,v6,v7,v8,v9,v10,v11,v12,v13,v14,v15;
        sc0_issue8(base+((int)list[k+0]<<10)+f, base+((int)list[k+1]<<10)+f,
                   base+((int)list[k+2]<<10)+f, base+((int)list[k+3]<<10)+f,
                   base+((int)list[k+4]<<10)+f, base+((int)list[k+5]<<10)+f,
                   base+((int)list[k+6]<<10)+f, base+((int)list[k+7]<<10)+f,
                   v0,v1,v2,v3,v4,v5,v6,v7);
        sc0_issue8(base+((int)list[k+8]<<10)+f,  base+((int)list[k+9]<<10)+f,
                   base+((int)list[k+10]<<10)+f, base+((int)list[k+11]<<10)+f,
                   base+((int)list[k+12]<<10)+f, base+((int)list[k+13]<<10)+f,
                   base+((int)list[k+14]<<10)+f, base+((int)list[k+15]<<10)+f,
                   v8,v9,v10,v11,v12,v13,v14,v15);
        asm volatile("s_waitcnt vmcnt(0)" ::: "memory");
        __builtin_amdgcn_sched_barrier(0);
        c=__fadd_rn(c,v0);  c=__fadd_rn(c,v1);  c=__fadd_rn(c,v2);  c=__fadd_rn(c,v3);
        c=__fadd_rn(c,v4);  c=__fadd_rn(c,v5);  c=__fadd_rn(c,v6);  c=__fadd_rn(c,v7);
        c=__fadd_rn(c,v8);  c=__fadd_rn(c,v9);  c=__fadd_rn(c,v10); c=__fadd_rn(c,v11);
        c=__fadd_rn(c,v12); c=__fadd_rn(c,v13); c=__fadd_rn(c,v14); c=__fadd_rn(c,v15);
    }
    if (k + 8 <= k1) {
        float v0,v1,v2,v3,v4,v5,v6,v7;
        sc0_ld8(base+((int)list[k+0]<<10)+f, base+((int)list[k+1]<<10)+f,
                base+((int)list[k+2]<<10)+f, base+((int)list[k+3]<<10)+f,
                base+((int)list[k+4]<<10)+f, base+((int)list[k+5]<<10)+f,
                base+((int)list[k+6]<<10)+f, base+((int)list[k+7]<<10)+f,
                v0,v1,v2,v3,v4,v5,v6,v7);
        c=__fadd_rn(c,v0); c=__fadd_rn(c,v1); c=__fadd_rn(c,v2); c=__fadd_rn(c,v3);
        c=__fadd_rn(c,v4); c=__fadd_rn(c,v5); c=__fadd_rn(c,v6); c=__fadd_rn(c,v7);
        k += 8;
    }
    for (; k < k1; ++k)
        c = __fadd_rn(c, sc0_ld(base + ((int)list[k] << 10) + f));
    return c;
}

// ---------- one-time init ----------
__global__ __launch_bounds__(256) void k_init(
    const float* __restrict__ W, float* __restrict__ wT,
    float* __restrict__ apreT_g, unsigned* __restrict__ bar)
{
    int idx = blockIdx.x * 256 + threadIdx.x;          // covers NIN*FF = 802816
    {
        int f = idx & (FF - 1);
        int i = idx >> 10;
        wT[idx] = W[f * NIN + i];                      // wT[i][f] = W[f][i]
    }
    apreT_g[idx] = 0.f;                                // 8 XCD copies
    apreT_g[idx + NIN * FF] = 0.f;
    if (idx < BARSZ) bar[idx] = 0u;                    // replay-safe reset
}

// ---------- Poisson encode (pure f32): p = image*0.2f; noise < p ----------
__global__ __launch_bounds__(256) void k_encode(
    const float* __restrict__ image, const float* __restrict__ noise,
    u64* __restrict__ prebits)
{
    int tid = blockIdx.x * 256 + threadIdx.x;
    int lane = threadIdx.x & 63;
    int word = tid >> 6;           // (t*BB + b)*NW + wd
    int wd = word % NW;
    int tb = word / NW;
    int b = tb & (BB - 1);
    int i = (wd << 6) + lane;
    bool s = false;
    if (i < NIN) {
        float pf = __fmul_rn(image[b * NIN + i], 0.2f);
        s = (noise[(size_t)tb * NIN + i] < pf);
    }
    u64 m = __ballot(s);
    if (lane == 0) prebits[word] = m;
}

// ---------- transposed prebits: prebitsT[t][i][wb] (bit = batch b) ----------
__global__ __launch_bounds__(256) void k_encode_t(
    const u64* __restrict__ prebits, u64* __restrict__ prebitsT)
{
    int tid = blockIdx.x * 256 + threadIdx.x;
    int b = tid & (BB - 1);
    int ti = tid >> 8;             // t*NIN + i
    int i = ti % NIN;
    int t = ti / NIN;
    u64 w = prebits[((size_t)t * BB + b) * NW + (i >> 6)];
    bool s = (w >> (i & 63)) & 1ull;
    u64 m = __ballot(s);
    if ((threadIdx.x & 63) == 0)
        prebitsT[(size_t)ti * 4 + ((threadIdx.x >> 6) & 3)] = m;
}

// ---------- index lists per (t,b): ascending i, KC=384 chunk marks ----------
__global__ __launch_bounds__(256) void k_lists(
    const u64* __restrict__ prebits, unsigned short* __restrict__ idxA,
    unsigned short* __restrict__ cntA)
{
    int tb = blockIdx.x * 256 + threadIdx.x;
    const u64* pb = prebits + (size_t)tb * NW;
    unsigned short* ia = idxA + (size_t)tb * CAPA;
    int n = 0, c1 = 0, c2 = 0;
    for (int wd = 0; wd < NW; ++wd) {
        u64 m = pb[wd];
        int boff = wd << 6;
        while (m) {
            int j = __builtin_ctzll(m); m &= m - 1;
            if (n < CAPA) ia[n] = (unsigned short)(boff + j);
            ++n;
        }
        if (wd == 5)  c1 = n;     // i < 384 boundary
        if (wd == 11) c2 = n;     // i < 768 boundary
    }
    if (n > CAPA) n = CAPA;
    if (c2 > n) c2 = n;
    if (c1 > c2) c1 = c2;
    cntA[tb * 4 + 0] = (unsigned short)c1;
    cntA[tb * 4 + 1] = (unsigned short)c2;
    cntA[tb * 4 + 2] = (unsigned short)n;
}

// ---------- b-lists per (t,i): ascending b ----------
__global__ __launch_bounds__(256) void k_listsT(
    const u64* __restrict__ prebitsT, unsigned char* __restrict__ idxB,
    unsigned short* __restrict__ cntB)
{
    int ti = blockIdx.x * 256 + threadIdx.x;
    if (ti >= TSTEPS * NIN) return;
    const u64* pt = prebitsT + (size_t)ti * 4;
    unsigned char* ib = idxB + (size_t)ti * CAPB;
    int n = 0;
    for (int wb = 0; wb < 4; ++wb) {
        u64 m = pt[wb];
        int boff = wb << 6;
        while (m) {
            int j = __builtin_ctzll(m); m &= m - 1;
            if (n < CAPB) ib[n] = (unsigned char)(boff + j);
            ++n;
        }
    }
    cntB[ti] = (unsigned short)(n > CAPB ? CAPB : n);
}

// ---------- persistent kernel: zero device-scope ops in steady state ----------
__global__ __launch_bounds__(TPB, 2) void k_run(
    float* __restrict__ wT, float* __restrict__ apreT_g, float* __restrict__ apost,
    const unsigned short* __restrict__ idxA, const unsigned short* __restrict__ cntA,
    const unsigned char* __restrict__ idxB, const unsigned short* __restrict__ cntB,
    const u64* __restrict__ prebitsT, u64* __restrict__ spkb,
    float* __restrict__ out, unsigned* __restrict__ bar,
    float dmem, float dpre, float dpost, float lrp, float lrm)
{
    __shared__ int shs[16];          // slice list for this XCD group
    __shared__ int shinfo[4];        // xcd, rank, nx, nsl
    __shared__ unsigned scnt[16];
    __shared__ int sbad;
    __shared__ float sap[8][256];    // per-wave Sp staging

    const int tix = threadIdx.x;
    const int wv = tix >> 6, lane = tix & 63;
    const int bid = blockIdx.x;

    // ===== RMW-free self-organization (one slot store + vector poll) =====
    unsigned* slot = bar;                       // [512]
    if (tix < 16) scnt[tix] = 0u;
    if (tix == 0) {
        unsigned x;
        asm volatile("s_getreg_b32 %0, hwreg(HW_REG_XCC_ID)" : "=s"(x));
        shinfo[0] = (int)(x & 7u);
        at_st(&slot[bid], (x & 7u) + 1u);
    }
    __syncthreads();
    const int xcd = shinfo[0];
    unsigned mv = 0;
    for (int rounds = 0;; ++rounds) {
        if (tix == 0) sbad = 0;
        __syncthreads();
        mv = at_ld(&slot[tix]);                 // TPB == NBLK: one slot each
        if (!mv) sbad = 1;
        __syncthreads();
        if (!sbad || rounds > (1 << 20)) break;
        __builtin_amdgcn_s_sleep(2);
    }
    atomicAdd(&scnt[mv - 1u], 1u);              // LDS
    if ((int)(mv - 1u) == xcd && tix < bid) atomicAdd(&scnt[8], 1u);
    __syncthreads();
    if (tix == 0) {
        int Kn = 0, gidx = 0;
        for (int x2 = 0; x2 < 8; ++x2)
            if (scnt[x2] > 0) { if (x2 == xcd) gidx = Kn; ++Kn; }
        int ns = 0;
        for (int s = 0; s < 16; ++s)
            if ((s % Kn) == gidx) shs[ns++] = s;
        shinfo[1] = (int)scnt[8];
        shinfo[2] = (int)scnt[xcd];
        shinfo[3] = ns;
    }
    __syncthreads();
    const int rank = shinfo[1], nx = shinfo[2], nsl = shinfo[3];
    const int nxw = nx * 8;
    const int wrank = rank * 8 + wv;
    const int nA = nsl << 8;          // (slice, b) units
    const int nB = nsl * NIN;         // (slice, i) units
    float* apx = apreT_g + (size_t)xcd * (BB * NIN);   // [i*256+b], XCD-local
    float* sapw = sap[wv];
    unsigned* arrive  = bar + 512 + xcd * 512;
    unsigned* release = bar + 4608 + xcd * 512;
    unsigned ep = 1;

    // register-resident per-unit state (owner wave fixed for the whole run)
#define A_STATE(Q) float memv##Q = 0.f, cntv##Q = 0.f, apov##Q = 0.f; u64 pbal##Q = 0ull;
    A_STATE(0) A_STATE(1) A_STATE(2) A_STATE(3)

#define DO_A(Q) do { \
    int u = wrank + (Q) * nxw; \
    if (u < nA) { \
        int sl = u >> 8, b = u & 255; \
        int slice = shs[sl]; \
        int f = (slice << 6) + lane; \
        apov##Q = __fadd_rn(__fmul_rn(apov##Q, dpost), \
                            (float)((pbal##Q >> lane) & 1ull)); \
        apost[(b << 10) + f] = apov##Q; \
        const unsigned short* ia = idxA + (size_t)(t * BB + b) * CAPA; \
        const unsigned short* ca = cntA + (size_t)(t * BB + b) * 4; \
        int c1 = ca[0], c2 = ca[1], c3 = ca[2]; \
        float I = 0.f; \
        I = __fadd_rn(I, foldList(wT, ia, 0,  c1, f)); \
        I = __fadd_rn(I, foldList(wT, ia, c1, c2, f)); \
        I = __fadd_rn(I, foldList(wT, ia, c2, c3, f)); \
        float mm = __fadd_rn(__fmul_rn(memv##Q, dmem), I); \
        bool spk = (mm >= 16.0f); \
        memv##Q = spk ? 0.f : mm; \
        if (spk) cntv##Q += 1.f; \
        pbal##Q = __ballot(spk); \
        if (lane == 0) spkb[(slice << 8) + b] = pbal##Q;   /* plain store */ \
    } \
} while (0)

    // store/poll barrier: no RMW; leader (rank 0) vector-polls arrivals
    auto xbar = [&]() {
        asm volatile("s_waitcnt vmcnt(0) lgkmcnt(0)" ::: "memory");
        __syncthreads();
        if (rank == 0) {
            for (int rounds = 0;; ++rounds) {
                if (tix == 0) sbad = 0;
                __syncthreads();
                if (tix > 0 && tix < nx && at_ld(&arrive[tix]) < ep) sbad = 1;
                __syncthreads();
                if (!sbad || rounds > (1 << 20)) break;
                __builtin_amdgcn_s_sleep(1);
            }
            if (tix < nx) at_st(&release[tix], ep);
        } else {
            if (tix == 0) {
                at_st(&arrive[rank], ep);
                unsigned spins = 0;
                while (at_ld(&release[rank]) < ep) {
                    if (++spins > (1u << 22)) break;
                    __builtin_amdgcn_s_sleep(8);
                }
            }
            __syncthreads();
        }
        ++ep;
    };

    for (int t = 0; t < TSTEPS; ++t) {
        // ===== phase A (wave-local; no device-scope ops) =====
        DO_A(0); DO_A(1); DO_A(2); DO_A(3);

        // apre update: coalesced float4 RMW per row (owner-stable; readers sc0)
        for (int r = wrank; r < NIN; r += nxw) {
            const u64* pt = prebitsT + ((size_t)t * NIN + r) * 4;
            u64 w0 = pt[0], w1 = pt[1], w2 = pt[2], w3 = pt[3];
            int bb = lane << 2;
            u64 wsel = (bb & 128) ? ((bb & 64) ? w3 : w2)
                                  : ((bb & 64) ? w1 : w0);
            int s0 = bb & 63;
            f4* vp = (f4*)(apx + ((size_t)r << 8) + bb);
            f4 v = *vp;
            v.x = __fadd_rn(__fmul_rn(v.x, dpre), (float)((wsel >> s0) & 1ull));
            v.y = __fadd_rn(__fmul_rn(v.y, dpre), (float)((wsel >> (s0+1)) & 1ull));
            v.z = __fadd_rn(__fmul_rn(v.z, dpre), (float)((wsel >> (s0+2)) & 1ull));
            v.w = __fadd_rn(__fmul_rn(v.w, dpre), (float)((wsel >> (s0+3)) & 1ull));
            *vp = v;
        }

        if (t == TSTEPS - 1) break;
        xbar();

        // ===== phase B (wave-local units; masks rebuilt in registers) =====
        int cursl = -1;
        u64 tm0 = 0, tm1 = 0, tm2 = 0, tm3 = 0;   // lane f's b-masks
        for (int q = 0;; ++q) {
            int u = wrank + q * nxw;
            if (u >= nB) break;
            int sl = u / NIN, i = u - sl * NIN;
            int slice = shs[sl];
            int f = (slice << 6) + lane;

            if (sl != cursl) {        // 64x64 bit-transpose of slice ballots
                cursl = sl;
                const u64* sb = spkb + (slice << 8);
                u64 v0, v1, v2, v3;   // lane j holds ballot of b = wb*64+j
                sc0_ld64x4(sb + lane, sb + 64 + lane, sb + 128 + lane, sb + 192 + lane,
                           v0, v1, v2, v3);
                tm0 = tm1 = tm2 = tm3 = 0ull;
                #pragma unroll 8
                for (int fp = 0; fp < 64; ++fp) {
                    u64 b0 = __ballot((int)((v0 >> fp) & 1ull));
                    u64 b1 = __ballot((int)((v1 >> fp) & 1ull));
                    u64 b2 = __ballot((int)((v2 >> fp) & 1ull));
                    u64 b3 = __ballot((int)((v3 >> fp) & 1ull));
                    if (lane == fp) { tm0 = b0; tm1 = b1; tm2 = b2; tm3 = b3; }
                }
            }

            // Sm: list-order fold over pre(i) of apost[b',f]  (sc0 batched)
            const unsigned char* ib = idxB + (size_t)(t * NIN + i) * CAPB;
            int cb = cntB[t * NIN + i];
            float Sm = foldList(apost, ib, 0, cb, f);

            // stage apre row i into this wave's LDS buffer (sc0, coalesced)
            f4 rv = sc0_ld4((const f4*)(apx + ((size_t)i << 8) + (lane << 2)));
            *(f4*)(sapw + (lane << 2)) = rv;
            asm volatile("s_waitcnt lgkmcnt(0)" ::: "memory");
            __builtin_amdgcn_sched_barrier(0);

            // Sp: ascending-b fold over spk(f) of apre[b',i] (LDS gather)
            float Sp = 0.f;
            u64 m;
            m = tm0; while (m) { int j = __builtin_ctzll(m); m &= m - 1;
                                 Sp = __fadd_rn(Sp, sapw[j]); }
            m = tm1; while (m) { int j = __builtin_ctzll(m); m &= m - 1;
                                 Sp = __fadd_rn(Sp, sapw[64 + j]); }
            m = tm2; while (m) { int j = __builtin_ctzll(m); m &= m - 1;
                                 Sp = __fadd_rn(Sp, sapw[128 + j]); }
            m = tm3; while (m) { int j = __builtin_ctzll(m); m &= m - 1;
                                 Sp = __fadd_rn(Sp, sapw[192 + j]); }

            int wi = (i << 10) + f;            // owner-stable row: plain RMW
            float w = wT[wi];
            w = __fadd_rn(w, __fmul_rn(lrp, Sp));
            w = __fsub_rn(w, __fmul_rn(lrm, Sm));
            w = fminf(fmaxf(w, 0.f), 1.f);
            wT[wi] = w;
        }
        xbar();
    }

    // spike counts from registers (every (b,f) covered exactly once)
#define DO_OUT(Q) do { \
    int u = wrank + (Q) * nxw; \
    if (u < nA) { \
        int sl = u >> 8, b = u & 255; \
        int f = (shs[sl] << 6) + lane; \
        out[(b << 10) + f] = cntv##Q; \
    } \
} while (0)
    DO_OUT(0); DO_OUT(1); DO_OUT(2); DO_OUT(3);
}

extern "C" void kernel_launch(void* const* d_in, const int* in_sizes, int n_in,
                              void* d_out, int out_size, void* d_ws, size_t ws_size,
                              hipStream_t stream)
{
    const float* image = (const float*)d_in[0];
    const float* W     = (const float*)d_in[1];
    const float* noise = (const float*)d_in[2];
    float* out = (float*)d_out;

    char* p = (char*)d_ws;
    float* wT      = (float*)p; p += (size_t)NIN * FF * 4;              // 3.2 MB
    float* apreT_g = (float*)p; p += (size_t)8 * BB * NIN * 4;          // 6.4 MB
    float* apost   = (float*)p; p += (size_t)BB * FF * 4;               // 1 MB
    u64* prebits   = (u64*)p;   p += (size_t)TSTEPS * BB * NW * 8;      // 2.66 MB
    u64* prebitsT  = (u64*)p;   p += (size_t)TSTEPS * NIN * 4 * 8;      // 2.51 MB
    u64* spkb      = (u64*)p;   p += (size_t)16 * 256 * 8;              // 32 KB
    unsigned short* idxA = (unsigned short*)p; p += (size_t)TSTEPS * BB * CAPA * 2;
    unsigned short* cntA = (unsigned short*)p; p += (size_t)TSTEPS * BB * 4 * 2;
    unsigned char*  idxB = (unsigned char*)p;  p += (size_t)TSTEPS * NIN * CAPB;
    unsigned short* cntB = (unsigned short*)p; p += (size_t)TSTEPS * NIN * 2;
    unsigned* bar        = (unsigned*)p;       p += (size_t)BARSZ * 4;  // 34.8 KB

    float dmem = (float)exp(-1.0 / 20.0);   // np.float32(np.exp(-0.05))
    float dpre = dmem, dpost = dmem;
    float lrp = (float)(0.01 / 256.0);
    float lrm = (float)(0.012 / 256.0);

    k_init<<<(NIN * FF) / 256, 256, 0, stream>>>(W, wT, apreT_g, bar);
    k_encode<<<(TSTEPS * BB * NW * 64) / 256, 256, 0, stream>>>(image, noise, prebits);
    k_encode_t<<<(TSTEPS * NIN * BB) / 256, 256, 0, stream>>>(prebits, prebitsT);
    k_lists<<<(TSTEPS * BB) / 256, 256, 0, stream>>>(prebits, idxA, cntA);
    k_listsT<<<(TSTEPS * NIN + 255) / 256, 256, 0, stream>>>(prebitsT, idxB, cntB);

    k_run<<<NBLK, TPB, 0, stream>>>(
        wT, apreT_g, apost, idxA, cntA, idxB, cntB,
        prebitsT, spkb, out, bar, dmem, dpre, dpost, lrp, lrm);
}

// Round 15
// 4926.383 us; speedup vs baseline: 1.2938x; 1.2938x over previous
//
#include <hip/hip_runtime.h>
#include <math.h>

#define TSTEPS 100
#define BB 256
#define FF 1024
#define NIN 784
#define NW 13           // 13*64 = 832 >= 784 bits per input row
#define CAPA 192        // max pre-spikes per (t,b)
#define CAPB 128        // max pre-spikes per (t,i)
#define NBLK 1024       // 4 blocks/CU
#define TPB 256         // 4 waves/block
#define BARSZ 17408     // u32: slots[1024] + arrive[8*1024] + release[8*1024]

typedef unsigned long long u64;
typedef float f4 __attribute__((ext_vector_type(4)));

// agent-scope atomics (coherence point; r8/r11-proven for masks/flags)
__device__ __forceinline__ unsigned at_ld(unsigned* p) {
    return __hip_atomic_load(p, __ATOMIC_RELAXED, __HIP_MEMORY_SCOPE_AGENT);
}
__device__ __forceinline__ void at_st(unsigned* p, unsigned v) {
    __hip_atomic_store(p, v, __ATOMIC_RELAXED, __HIP_MEMORY_SCOPE_AGENT);
}
__device__ __forceinline__ u64 at_ld64(u64* p) {
    return __hip_atomic_load(p, __ATOMIC_RELAXED, __HIP_MEMORY_SCOPE_AGENT);
}
__device__ __forceinline__ void at_st64(u64* p, u64 v) {
    __hip_atomic_store(p, v, __ATOMIC_RELAXED, __HIP_MEMORY_SCOPE_AGENT);
}

// L1-bypassing loads (r10/r11-proven syntax); values served from XCD-local L2
__device__ __forceinline__ float sc0_ld(const float* p) {
    float v;
    asm volatile("global_load_dword %0, %1, off sc0\n\t"
                 "s_waitcnt vmcnt(0)"
                 : "=v"(v) : "v"(p) : "memory");
    __builtin_amdgcn_sched_barrier(0);
    return v;
}
__device__ __forceinline__ f4 sc0_ld4(const f4* p) {
    f4 v;
    asm volatile("global_load_dwordx4 %0, %1, off sc0\n\t"
                 "s_waitcnt vmcnt(0)"
                 : "=v"(v) : "v"(p) : "memory");
    __builtin_amdgcn_sched_barrier(0);
    return v;
}
__device__ __forceinline__ void sc0_issue8(
    const float* p0, const float* p1, const float* p2, const float* p3,
    const float* p4, const float* p5, const float* p6, const float* p7,
    float& v0, float& v1, float& v2, float& v3,
    float& v4, float& v5, float& v6, float& v7)
{
    asm volatile(
        "global_load_dword %0, %8, off sc0\n\t"
        "global_load_dword %1, %9, off sc0\n\t"
        "global_load_dword %2, %10, off sc0\n\t"
        "global_load_dword %3, %11, off sc0\n\t"
        "global_load_dword %4, %12, off sc0\n\t"
        "global_load_dword %5, %13, off sc0\n\t"
        "global_load_dword %6, %14, off sc0\n\t"
        "global_load_dword %7, %15, off sc0"
        : "=&v"(v0),"=&v"(v1),"=&v"(v2),"=&v"(v3),
          "=&v"(v4),"=&v"(v5),"=&v"(v6),"=&v"(v7)
        : "v"(p0),"v"(p1),"v"(p2),"v"(p3),"v"(p4),"v"(p5),"v"(p6),"v"(p7)
        : "memory");
}
__device__ __forceinline__ void sc0_ld8(
    const float* p0, const float* p1, const float* p2, const float* p3,
    const float* p4, const float* p5, const float* p6, const float* p7,
    float& v0, float& v1, float& v2, float& v3,
    float& v4, float& v5, float& v6, float& v7)
{
    sc0_issue8(p0,p1,p2,p3,p4,p5,p6,p7, v0,v1,v2,v3,v4,v5,v6,v7);
    asm volatile("s_waitcnt vmcnt(0)" ::: "memory");
    __builtin_amdgcn_sched_barrier(0);
}

// sequential f32 fold over base[list[k]<<10 + f], ascending k — the VERIFIED
// numpy fold order; batching changes only load timing, never add order.
// (r11-verified form: full vmcnt(0) drain per batch.)
template <typename IDX>
__device__ __forceinline__ float foldList(
    const float* __restrict__ base, const IDX* __restrict__ list,
    int k0, int k1, int f)
{
    float c = 0.f;
    int k = k0;
    for (; k + 16 <= k1; k += 16) {
        float v0,v1,v2,v3,v4,v5,v6,v7,v8,v9,v10,v11,v12,v13,v14,v15;
        sc0_issue8(base+((int)list[k+0]<<10)+f, base+((int)list[k+1]<<10)+f,
                   base+((int)list[k+2]<<10)+f, base+((int)list[k+3]<<10)+f,
                   base+((int)list[k+4]<<10)+f, base+((int)list[k+5]<<10)+f,
                   base+((int)list[k+6]<<10)+f, base+((int)list[k+7]<<10)+f,
                   v0,v1,v2,v3,v4,v5,v6,v7);
        sc0_issue8(base+((int)list[k+8]<<10)+f,  base+((int)list[k+9]<<10)+f,
                   base+((int)list[k+10]<<10)+f, base+((int)list[k+11]<<10)+f,
                   base+((int)list[k+12]<<10)+f, base+((int)list[k+13]<<10)+f,
                   base+((int)list[k+14]<<10)+f, base+((int)list[k+15]<<10)+f,
                   v8,v9,v10,v11,v12,v13,v14,v15);
        asm volatile("s_waitcnt vmcnt(0)" ::: "memory");
        __builtin_amdgcn_sched_barrier(0);
        c=__fadd_rn(c,v0);  c=__fadd_rn(c,v1);  c=__fadd_rn(c,v2);  c=__fadd_rn(c,v3);
        c=__fadd_rn(c,v4);  c=__fadd_rn(c,v5);  c=__fadd_rn(c,v6);  c=__fadd_rn(c,v7);
        c=__fadd_rn(c,v8);  c=__fadd_rn(c,v9);  c=__fadd_rn(c,v10); c=__fadd_rn(c,v11);
        c=__fadd_rn(c,v12); c=__fadd_rn(c,v13); c=__fadd_rn(c,v14); c=__fadd_rn(c,v15);
    }
    if (k + 8 <= k1) {
        float v0,v1,v2,v3,v4,v5,v6,v7;
        sc0_ld8(base+((int)list[k+0]<<10)+f, base+((int)list[k+1]<<10)+f,
                base+((int)list[k+2]<<10)+f, base+((int)list[k+3]<<10)+f,
                base+((int)list[k+4]<<10)+f, base+((int)list[k+5]<<10)+f,
                base+((int)list[k+6]<<10)+f, base+((int)list[k+7]<<10)+f,
                v0,v1,v2,v3,v4,v5,v6,v7);
        c=__fadd_rn(c,v0); c=__fadd_rn(c,v1); c=__fadd_rn(c,v2); c=__fadd_rn(c,v3);
        c=__fadd_rn(c,v4); c=__fadd_rn(c,v5); c=__fadd_rn(c,v6); c=__fadd_rn(c,v7);
        k += 8;
    }
    for (; k < k1; ++k)
        c = __fadd_rn(c, sc0_ld(base + ((int)list[k] << 10) + f));
    return c;
}

// ---------- one-time init ----------
__global__ __launch_bounds__(256) void k_init(
    const float* __restrict__ W, float* __restrict__ wT,
    float* __restrict__ apreT_g, float* __restrict__ apost,
    u64* __restrict__ spkT, unsigned* __restrict__ bar)
{
    int idx = blockIdx.x * 256 + threadIdx.x;          // covers NIN*FF = 802816
    {
        int f = idx & (FF - 1);
        int i = idx >> 10;
        wT[idx] = W[f * NIN + i];                      // wT[i][f] = W[f][i]
    }
    apreT_g[idx] = 0.f;                                // 8 XCD copies
    apreT_g[idx + NIN * FF] = 0.f;
    if (idx < BB * FF) apost[idx] = 0.f;
    if (idx < 2 * FF * 4) spkT[idx] = 0ull;
    if (idx < BARSZ) bar[idx] = 0u;                    // replay-safe reset
}

// ---------- Poisson encode (pure f32): p = image*0.2f; noise < p ----------
__global__ __launch_bounds__(256) void k_encode(
    const float* __restrict__ image, const float* __restrict__ noise,
    u64* __restrict__ prebits)
{
    int tid = blockIdx.x * 256 + threadIdx.x;
    int lane = threadIdx.x & 63;
    int word = tid >> 6;           // (t*BB + b)*NW + wd
    int wd = word % NW;
    int tb = word / NW;
    int b = tb & (BB - 1);
    int i = (wd << 6) + lane;
    bool s = false;
    if (i < NIN) {
        float pf = __fmul_rn(image[b * NIN + i], 0.2f);
        s = (noise[(size_t)tb * NIN + i] < pf);
    }
    u64 m = __ballot(s);
    if (lane == 0) prebits[word] = m;
}

// ---------- transposed prebits: prebitsT[t][i][wb] (bit = batch b) ----------
__global__ __launch_bounds__(256) void k_encode_t(
    const u64* __restrict__ prebits, u64* __restrict__ prebitsT)
{
    int tid = blockIdx.x * 256 + threadIdx.x;
    int b = tid & (BB - 1);
    int ti = tid >> 8;             // t*NIN + i
    int i = ti % NIN;
    int t = ti / NIN;
    u64 w = prebits[((size_t)t * BB + b) * NW + (i >> 6)];
    bool s = (w >> (i & 63)) & 1ull;
    u64 m = __ballot(s);
    if ((threadIdx.x & 63) == 0)
        prebitsT[(size_t)ti * 4 + ((threadIdx.x >> 6) & 3)] = m;
}

// ---------- index lists per (t,b): ascending i, KC=384 chunk marks ----------
__global__ __launch_bounds__(256) void k_lists(
    const u64* __restrict__ prebits, unsigned short* __restrict__ idxA,
    unsigned short* __restrict__ cntA)
{
    int tb = blockIdx.x * 256 + threadIdx.x;
    const u64* pb = prebits + (size_t)tb * NW;
    unsigned short* ia = idxA + (size_t)tb * CAPA;
    int n = 0, c1 = 0, c2 = 0;
    for (int wd = 0; wd < NW; ++wd) {
        u64 m = pb[wd];
        int boff = wd << 6;
        while (m) {
            int j = __builtin_ctzll(m); m &= m - 1;
            if (n < CAPA) ia[n] = (unsigned short)(boff + j);
            ++n;
        }
        if (wd == 5)  c1 = n;     // i < 384 boundary
        if (wd == 11) c2 = n;     // i < 768 boundary
    }
    if (n > CAPA) n = CAPA;
    if (c2 > n) c2 = n;
    if (c1 > c2) c1 = c2;
    cntA[tb * 4 + 0] = (unsigned short)c1;
    cntA[tb * 4 + 1] = (unsigned short)c2;
    cntA[tb * 4 + 2] = (unsigned short)n;
}

// ---------- b-lists per (t,i): ascending b ----------
__global__ __launch_bounds__(256) void k_listsT(
    const u64* __restrict__ prebitsT, unsigned char* __restrict__ idxB,
    unsigned short* __restrict__ cntB)
{
    int ti = blockIdx.x * 256 + threadIdx.x;
    if (ti >= TSTEPS * NIN) return;
    const u64* pt = prebitsT + (size_t)ti * 4;
    unsigned char* ib = idxB + (size_t)ti * CAPB;
    int n = 0;
    for (int wb = 0; wb < 4; ++wb) {
        u64 m = pt[wb];
        int boff = wb << 6;
        while (m) {
            int j = __builtin_ctzll(m); m &= m - 1;
            if (n < CAPB) ib[n] = (unsigned char)(boff + j);
            ++n;
        }
    }
    cntB[ti] = (unsigned short)(n > CAPB ? CAPB : n);
}

// ---------- persistent kernel (r11 verbatim; ONLY phase-B order changed) ----------
__global__ __launch_bounds__(TPB, 4) void k_run(
    float* __restrict__ wT, float* __restrict__ apreT_g, float* __restrict__ apost,
    const unsigned short* __restrict__ idxA, const unsigned short* __restrict__ cntA,
    const unsigned char* __restrict__ idxB, const unsigned short* __restrict__ cntB,
    const u64* __restrict__ prebitsT, u64* __restrict__ spkT,
    float* __restrict__ out, unsigned* __restrict__ bar,
    float dmem, float dpre, float dpost, float lrp, float lrm)
{
    __shared__ int shs[16];          // slice list for this XCD group
    __shared__ int shinfo[4];        // xcd, rank, nx, nsl
    __shared__ unsigned scnt[9];
    __shared__ int sbad;
    __shared__ float sap[4][256];    // per-wave Sp staging

    const int tix = threadIdx.x;
    const int wv = tix >> 6, lane = tix & 63;
    const int bid = blockIdx.x;

    // ===== RMW-free self-organization (r11-proven, verbatim) =====
    unsigned* slot = bar;                       // [1024]
    if (tix < 9) scnt[tix] = 0u;
    if (tix == 0) {
        unsigned x;
        asm volatile("s_getreg_b32 %0, hwreg(HW_REG_XCC_ID)" : "=s"(x));
        shinfo[0] = (int)(x & 7u);
        at_st(&slot[bid], (x & 7u) + 1u);
    }
    __syncthreads();
    const int xcd = shinfo[0];
    unsigned mv0, mv1, mv2, mv3;
    for (int rounds = 0;; ++rounds) {
        if (tix == 0) sbad = 0;
        __syncthreads();
        mv0 = at_ld(&slot[tix]);
        mv1 = at_ld(&slot[256 + tix]);
        mv2 = at_ld(&slot[512 + tix]);
        mv3 = at_ld(&slot[768 + tix]);
        if (!(mv0 && mv1 && mv2 && mv3)) sbad = 1;
        __syncthreads();
        if (!sbad || rounds > (1 << 20)) break;
        __builtin_amdgcn_s_sleep(2);
    }
    {
        atomicAdd(&scnt[mv0 - 1u], 1u);
        atomicAdd(&scnt[mv1 - 1u], 1u);
        atomicAdd(&scnt[mv2 - 1u], 1u);
        atomicAdd(&scnt[mv3 - 1u], 1u);
        unsigned r = 0;
        if ((int)(mv0 - 1u) == xcd && tix < bid) r++;
        if ((int)(mv1 - 1u) == xcd && 256 + tix < bid) r++;
        if ((int)(mv2 - 1u) == xcd && 512 + tix < bid) r++;
        if ((int)(mv3 - 1u) == xcd && 768 + tix < bid) r++;
        if (r) atomicAdd(&scnt[8], r);
        __syncthreads();
        if (tix == 0) {
            int Kn = 0, gidx = 0;
            for (int x2 = 0; x2 < 8; ++x2)
                if (scnt[x2] > 0) { if (x2 == xcd) gidx = Kn; ++Kn; }
            int ns = 0;
            for (int s = 0; s < 16; ++s)
                if ((s % Kn) == gidx) shs[ns++] = s;
            shinfo[1] = (int)scnt[8];
            shinfo[2] = (int)scnt[xcd];
            shinfo[3] = ns;
        }
        __syncthreads();
    }
    const int rank = shinfo[1], nx = shinfo[2], nsl = shinfo[3];
    const int nxw = nx * 4;
    const int wrank = rank * 4 + wv;
    const int nA = nsl << 8;          // (slice, b) units
    const int nB = nsl * NIN;         // (slice, i) units
    float* apx = apreT_g + (size_t)xcd * (BB * NIN);   // [i*256+b], XCD-local
    float* sapw = sap[wv];
    unsigned* arrive  = bar + 1024 + xcd * 1024;
    unsigned* release = bar + 9216 + xcd * 1024;
    unsigned ep = 1;

#define A_STATE(Q) float memv##Q = 0.f, cntv##Q = 0.f, apov##Q = 0.f; u64 pbal##Q = 0ull;
    A_STATE(0) A_STATE(1) A_STATE(2) A_STATE(3)

#define DO_A(Q) do { \
    int u = wrank + (Q) * nxw; \
    if (u < nA) { \
        int sl = u >> 8, b = u & 255; \
        int f = (shs[sl] << 6) + lane; \
        apov##Q = __fadd_rn(__fmul_rn(apov##Q, dpost), \
                            (float)((pbal##Q >> lane) & 1ull)); \
        apost[(b << 10) + f] = apov##Q; \
        const unsigned short* ia = idxA + (size_t)(t * BB + b) * CAPA; \
        const unsigned short* ca = cntA + (size_t)(t * BB + b) * 4; \
        int c1 = ca[0], c2 = ca[1], c3 = ca[2]; \
        float I = 0.f; \
        I = __fadd_rn(I, foldList(wT, ia, 0,  c1, f)); \
        I = __fadd_rn(I, foldList(wT, ia, c1, c2, f)); \
        I = __fadd_rn(I, foldList(wT, ia, c2, c3, f)); \
        float mm = __fadd_rn(__fmul_rn(memv##Q, dmem), I); \
        bool spk = (mm >= 16.0f); \
        memv##Q = spk ? 0.f : mm; \
        if (spk) { \
            cntv##Q += 1.f; \
            atomicOr(&cur[(f << 2) | (b >> 6)], 1ull << (b & 63)); \
        } \
        pbal##Q = __ballot(spk); \
    } \
} while (0)

    // store/poll barrier with agent-scope flags (r11-proven verbatim)
    auto xbar = [&]() {
        asm volatile("s_waitcnt vmcnt(0) lgkmcnt(0)" ::: "memory");
        __syncthreads();
        if (rank == 0) {
            for (int rounds = 0;; ++rounds) {
                if (tix == 0) sbad = 0;
                __syncthreads();
                bool ok = true;
                #pragma unroll
                for (int kk = 0; kk < 4; ++kk) {
                    int r = kk * 256 + tix;
                    if (r < nx && r > 0) ok &= (at_ld(&arrive[r]) >= ep);
                }
                if (!ok) sbad = 1;
                __syncthreads();
                if (!sbad || rounds > (1 << 20)) break;
                __builtin_amdgcn_s_sleep(4);
            }
            #pragma unroll
            for (int kk = 0; kk < 4; ++kk) {
                int r = kk * 256 + tix;
                if (r < nx) at_st(&release[r], ep);
            }
        } else {
            if (tix == 0) {
                at_st(&arrive[rank], ep);
                unsigned spins = 0;
                while (at_ld(&release[rank]) < ep) {
                    if (++spins > (1u << 22)) break;
                    __builtin_amdgcn_s_sleep(8);
                }
            }
            __syncthreads();
        }
        ++ep;
    };

    for (int t = 0; t < TSTEPS; ++t) {
        u64* cur = spkT + (size_t)(t & 1) * (FF * 4);
        u64* nxt = spkT + (size_t)((t + 1) & 1) * (FF * 4);

        // ===== phase A (wave-local units) =====
        DO_A(0); DO_A(1); DO_A(2); DO_A(3);

        // apre update: coalesced float4 RMW per row (owner-stable; readers sc0)
        for (int r = wrank; r < NIN; r += nxw) {
            const u64* pt = prebitsT + ((size_t)t * NIN + r) * 4;
            u64 w0 = pt[0], w1 = pt[1], w2 = pt[2], w3 = pt[3];
            int bb = lane << 2;
            u64 wsel = (bb & 128) ? ((bb & 64) ? w3 : w2)
                                  : ((bb & 64) ? w1 : w0);
            int s0 = bb & 63;
            f4* vp = (f4*)(apx + ((size_t)r << 8) + bb);
            f4 v = *vp;
            v.x = __fadd_rn(__fmul_rn(v.x, dpre), (float)((wsel >> s0) & 1ull));
            v.y = __fadd_rn(__fmul_rn(v.y, dpre), (float)((wsel >> (s0+1)) & 1ull));
            v.z = __fadd_rn(__fmul_rn(v.z, dpre), (float)((wsel >> (s0+2)) & 1ull));
            v.w = __fadd_rn(__fmul_rn(v.w, dpre), (float)((wsel >> (s0+3)) & 1ull));
            *vp = v;
        }
        // zero next-parity spike masks (atomic domain — must match atomicOr)
        for (int wd0 = rank * TPB + tix; wd0 < (nsl << 8); wd0 += nx * TPB) {
            int sl = wd0 >> 8, rest = wd0 & 255;
            int f = (shs[sl] << 6) + (rest >> 2);
            at_st64(&nxt[(f << 2) + (rest & 3)], 0ull);
        }

        if (t == TSTEPS - 1) break;
        xbar();

        // ===== phase B: slice-major unit order v = i*nsl + sl =====
        // With nxw even and nsl | nxw (typical), sl is constant per wave →
        // the 4 agent-scope mask loads hoist to once per step per wave.
        {
            int cursl = -1, f = 0;
            u64 m0 = 0, m1 = 0, m2 = 0, m3 = 0;
            for (int v = wrank; v < nB; v += nxw) {
                int sl = v % nsl;
                int i = v / nsl;
                if (sl != cursl) {
                    cursl = sl;
                    f = (shs[sl] << 6) + lane;
                    m0 = at_ld64(&cur[(f << 2) | 0]);
                    m1 = at_ld64(&cur[(f << 2) | 1]);
                    m2 = at_ld64(&cur[(f << 2) | 2]);
                    m3 = at_ld64(&cur[(f << 2) | 3]);
                }

                // Sm: list-order fold over pre(i) of apost[b',f]
                const unsigned char* ib = idxB + (size_t)(t * NIN + i) * CAPB;
                int cb = cntB[t * NIN + i];
                float Sm = foldList(apost, ib, 0, cb, f);

                // stage apre row i into this wave's LDS buffer (sc0, coalesced)
                f4 rv = sc0_ld4((const f4*)(apx + ((size_t)i << 8) + (lane << 2)));
                *(f4*)(sapw + (lane << 2)) = rv;
                asm volatile("s_waitcnt lgkmcnt(0)" ::: "memory");
                __builtin_amdgcn_sched_barrier(0);

                // Sp: ascending-b fold over spk(f) of apre[b',i] (LDS gather)
                float Sp = 0.f;
                u64 m;
                m = m0; while (m) { int j = __builtin_ctzll(m); m &= m - 1;
                                    Sp = __fadd_rn(Sp, sapw[j]); }
                m = m1; while (m) { int j = __builtin_ctzll(m); m &= m - 1;
                                    Sp = __fadd_rn(Sp, sapw[64 + j]); }
                m = m2; while (m) { int j = __builtin_ctzll(m); m &= m - 1;
                                    Sp = __fadd_rn(Sp, sapw[128 + j]); }
                m = m3; while (m) { int j = __builtin_ctzll(m); m &= m - 1;
                                    Sp = __fadd_rn(Sp, sapw[192 + j]); }

                int wi = (i << 10) + f;            // owner-stable row: plain RMW
                float w = wT[wi];
                w = __fadd_rn(w, __fmul_rn(lrp, Sp));
                w = __fsub_rn(w, __fmul_rn(lrm, Sm));
                w = fminf(fmaxf(w, 0.f), 1.f);
                wT[wi] = w;
            }
        }
        xbar();
    }

    // spike counts from registers (every (b,f) covered exactly once)
#define DO_OUT(Q) do { \
    int u = wrank + (Q) * nxw; \
    if (u < nA) { \
        int sl = u >> 8, b = u & 255; \
        int f = (shs[sl] << 6) + lane; \
        out[(b << 10) + f] = cntv##Q; \
    } \
} while (0)
    DO_OUT(0); DO_OUT(1); DO_OUT(2); DO_OUT(3);
}

extern "C" void kernel_launch(void* const* d_in, const int* in_sizes, int n_in,
                              void* d_out, int out_size, void* d_ws, size_t ws_size,
                              hipStream_t stream)
{
    const float* image = (const float*)d_in[0];
    const float* W     = (const float*)d_in[1];
    const float* noise = (const float*)d_in[2];
    float* out = (float*)d_out;

    char* p = (char*)d_ws;
    float* wT      = (float*)p; p += (size_t)NIN * FF * 4;              // 3.2 MB
    float* apreT_g = (float*)p; p += (size_t)8 * BB * NIN * 4;          // 6.4 MB
    float* apost   = (float*)p; p += (size_t)BB * FF * 4;               // 1 MB
    u64* prebits   = (u64*)p;   p += (size_t)TSTEPS * BB * NW * 8;      // 2.66 MB
    u64* prebitsT  = (u64*)p;   p += (size_t)TSTEPS * NIN * 4 * 8;      // 2.51 MB
    u64* spkT      = (u64*)p;   p += (size_t)2 * FF * 4 * 8;            // 64 KB
    unsigned short* idxA = (unsigned short*)p; p += (size_t)TSTEPS * BB * CAPA * 2;
    unsigned short* cntA = (unsigned short*)p; p += (size_t)TSTEPS * BB * 4 * 2;
    unsigned char*  idxB = (unsigned char*)p;  p += (size_t)TSTEPS * NIN * CAPB;
    unsigned short* cntB = (unsigned short*)p; p += (size_t)TSTEPS * NIN * 2;
    unsigned* bar        = (unsigned*)p;       p += (size_t)BARSZ * 4;  // 68 KB

    float dmem = (float)exp(-1.0 / 20.0);   // np.float32(np.exp(-0.05))
    float dpre = dmem, dpost = dmem;
    float lrp = (float)(0.01 / 256.0);
    float lrm = (float)(0.012 / 256.0);

    k_init<<<(NIN * FF) / 256, 256, 0, stream>>>(W, wT, apreT_g, apost, spkT, bar);
    k_encode<<<(TSTEPS * BB * NW * 64) / 256, 256, 0, stream>>>(image, noise, prebits);
    k_encode_t<<<(TSTEPS * NIN * BB) / 256, 256, 0, stream>>>(prebits, prebitsT);
    k_lists<<<(TSTEPS * BB) / 256, 256, 0, stream>>>(prebits, idxA, cntA);
    k_listsT<<<(TSTEPS * NIN + 255) / 256, 256, 0, stream>>>(prebitsT, idxB, cntB);

    k_run<<<NBLK, TPB, 0, stream>>>(
        wT, apreT_g, apost, idxA, cntA, idxB, cntB,
        prebitsT, spkT, out, bar, dmem, dpre, dpost, lrp, lrm);
}